// Round 1
// baseline (205.865 us; speedup 1.0000x reference)
//
#include <hip/hip_runtime.h>

// out[b, i*4+p, j*4+q] = sum_{kh,kw} w[p*4+q][kh*16+kw] * x[b][i*8+kh][j*8+kw]
// x: [32,1024,1024] f32, w: [16,256] f32, out: [32,508,508] f32
// 127x127 patches/image; block = 16x16 patches; LDS tile 136x136 f32 (swizzled float4 granules).

#define TI 16
#define TJ 16
#define REG_ROWS 136          // (TI-1)*8 + 16
#define ROW_G    34           // 136/4 float4 granules per row
#define NG       (REG_ROWS * ROW_G)   // 4624 granules = 73984 B

__global__ __launch_bounds__(256, 2)
void conv_patch_linear(const float* __restrict__ x,
                       const float* __restrict__ w,
                       float* __restrict__ out) {
    __shared__ float4 lds4[NG];

    const int tid = threadIdx.x;
    const int b   = blockIdx.z;
    const int i0  = blockIdx.y * TI;   // patch-row base of this tile
    const int j0  = blockIdx.x * TJ;   // patch-col base

    const int xbase = b * (1024 * 1024);

    // ---- stage global -> LDS, granule-swizzled (involution: s ^= (s>>3)&3) ----
    for (int g = tid; g < NG; g += 256) {
        int row = g / ROW_G;
        int s   = g - row * ROW_G;
        int src = s ^ ((s >> 3) & 3);          // source granule for this slot
        int grow = i0 * 8 + row;  if (grow > 1023) grow = 1023;   // edge-tile clamp
        int gcol = j0 * 8 + src * 4; if (gcol > 1020) gcol = 1020;
        lds4[g] = *reinterpret_cast<const float4*>(x + xbase + grow * 1024 + gcol);
    }
    __syncthreads();

    const int pj = tid & 15;   // patch col within tile
    const int pi = tid >> 4;   // patch row within tile

    float acc[16];
    #pragma unroll
    for (int o = 0; o < 16; ++o) acc[o] = 0.f;

    #pragma unroll 2
    for (int kh = 0; kh < 16; ++kh) {
        const int rbase = (pi * 8 + kh) * ROW_G;
        #pragma unroll
        for (int kq = 0; kq < 4; ++kq) {
            const int c  = pj * 2 + kq;            // granule of col pj*8 + kq*4
            const int sl = c ^ ((c >> 3) & 3);     // swizzled slot (read side)
            const float4 xv = lds4[rbase + sl];
            const float* wp = w + kh * 16 + kq * 4;
            #pragma unroll
            for (int o = 0; o < 16; ++o) {
                const float4 wv = *reinterpret_cast<const float4*>(wp + o * 256);
                acc[o] = fmaf(xv.x, wv.x, acc[o]);
                acc[o] = fmaf(xv.y, wv.y, acc[o]);
                acc[o] = fmaf(xv.z, wv.z, acc[o]);
                acc[o] = fmaf(xv.w, wv.w, acc[o]);
            }
        }
    }

    // ---- store: patch (ip,jp) owns out rows ip*4..+3, cols jp*4..+3 ----
    const int ip = i0 + pi;
    const int jp = j0 + pj;
    if (ip < 127 && jp < 127) {
        float* op = out + b * (508 * 508) + (ip * 4) * 508 + jp * 4;
        #pragma unroll
        for (int p = 0; p < 4; ++p) {
            float4 v = make_float4(acc[p * 4 + 0], acc[p * 4 + 1],
                                   acc[p * 4 + 2], acc[p * 4 + 3]);
            *reinterpret_cast<float4*>(op + p * 508) = v;
        }
    }
}

extern "C" void kernel_launch(void* const* d_in, const int* in_sizes, int n_in,
                              void* d_out, int out_size, void* d_ws, size_t ws_size,
                              hipStream_t stream) {
    const float* x = (const float*)d_in[0];
    const float* w = (const float*)d_in[1];
    float* out = (float*)d_out;
    dim3 grid(8, 8, 32);   // (j-tiles, i-tiles, batch); 127 patches -> 8 tiles of 16 (last=15)
    conv_patch_linear<<<grid, dim3(256, 1, 1), 0, stream>>>(x, w, out);
}

// Round 2
// 79.112 us; speedup vs baseline: 2.6022x; 2.6022x over previous
//
#include <hip/hip_runtime.h>

// out[b, i*4+p, j*4+q] = sum_k w[p*4+q][k] * patch(b,i,j)[k],  k = kh*16+kw
// via bf16 MFMA 16x16x32: A = 16 patches x K, B = K x 16 outputs.
// Block = 4 waves; wave w handles patch-row i0+w, 16 patches along j.
// LDS: bf16 x-tile [40][136] (4 patch-rows halo x 16 patch-cols halo).

typedef __attribute__((ext_vector_type(8))) short short8;
typedef __attribute__((ext_vector_type(4))) float f32x4;

#define LDSW 136
#define ROWS 40
#define NG4  (ROWS * 34)   // 1360 float4 granules to stage

__device__ __forceinline__ unsigned short f2bf(float f) {
    unsigned int u = __builtin_bit_cast(unsigned int, f);
    u = (u + 0x7fffu + ((u >> 16) & 1u)) >> 16;   // RNE
    return (unsigned short)u;
}

__global__ __launch_bounds__(256, 4)
void conv_mfma(const float* __restrict__ x,
               const float* __restrict__ w,
               float* __restrict__ out) {
    __shared__ unsigned short lds[ROWS * LDSW];

    const int tid  = threadIdx.x;
    const int lane = tid & 63;
    const int wv   = tid >> 6;            // wave -> patch row i0+wv
    const int b    = blockIdx.z;
    const int i0   = blockIdx.y * 4;
    const int j0   = blockIdx.x * 16;

    const float* xb = x + (size_t)b * (1024 * 1024);

    // ---- weight fragments: lane holds B[k = s*32 + (lane>>4)*8 + r][o = lane&15]
    //      = w[o][s*32 + (lane>>4)*8 + r], 8 contiguous fp32 -> bf16x8
    const int o    = lane & 15;
    const int kblk = (lane >> 4) & 3;
    short8 bfrag[8];
    #pragma unroll
    for (int s = 0; s < 8; ++s) {
        const float* wp = w + o * 256 + s * 32 + kblk * 8;
        float4 w0 = *(const float4*)wp;
        float4 w1 = *(const float4*)(wp + 4);
        short8 f;
        f[0] = (short)f2bf(w0.x); f[1] = (short)f2bf(w0.y);
        f[2] = (short)f2bf(w0.z); f[3] = (short)f2bf(w0.w);
        f[4] = (short)f2bf(w1.x); f[5] = (short)f2bf(w1.y);
        f[6] = (short)f2bf(w1.z); f[7] = (short)f2bf(w1.w);
        bfrag[s] = f;
    }

    // ---- stage x tile: 40 rows x 136 cols fp32 -> bf16 LDS ----
    for (int g = tid; g < NG4; g += 256) {
        int row = g / 34;
        int c4  = g - row * 34;
        int grow = i0 * 8 + row;      if (grow > 1023) grow = 1023;
        int gcol = j0 * 8 + c4 * 4;   if (gcol > 1020) gcol = 1020;
        float4 v = *(const float4*)(xb + grow * 1024 + gcol);
        ushort4 h;
        h.x = f2bf(v.x); h.y = f2bf(v.y); h.z = f2bf(v.z); h.w = f2bf(v.w);
        *(ushort4*)&lds[row * LDSW + c4 * 4] = h;
    }
    __syncthreads();

    // ---- A fragments: lane holds A[m = lane&15][k = (lane>>4)*8 + r]
    //      k -> kh = 2s + (lane>>5), kw = ((lane>>4)&1)*8 + r
    //      LDS elem = [wv*8 + kh][m*8 + ((lane>>4)&1)*8]
    const unsigned short* abase =
        &lds[(wv * 8 + (lane >> 5)) * LDSW + (lane & 15) * 8 + ((lane >> 4) & 1) * 8];

    f32x4 acc = {0.f, 0.f, 0.f, 0.f};
    #pragma unroll
    for (int s = 0; s < 8; ++s) {
        short8 a = *(const short8*)(abase + 2 * s * LDSW);
        acc = __builtin_amdgcn_mfma_f32_16x16x32_bf16(a, bfrag[s], acc, 0, 0, 0);
    }

    // ---- epilogue: C[row = patch m = (lane>>4)*4 + r][col = o = lane&15] ----
    const int ip = i0 + wv;
    if (ip < 127) {
        const int p = o >> 2, q = o & 3;
        float* ob = out + (size_t)b * (508 * 508) + (ip * 4 + p) * 508 + q;
        #pragma unroll
        for (int r = 0; r < 4; ++r) {
            int m  = (lane >> 4) * 4 + r;
            int jp = j0 + m;
            if (jp < 127) ob[jp * 4] = acc[r];
        }
    }
}

extern "C" void kernel_launch(void* const* d_in, const int* in_sizes, int n_in,
                              void* d_out, int out_size, void* d_ws, size_t ws_size,
                              hipStream_t stream) {
    const float* x = (const float*)d_in[0];
    const float* w = (const float*)d_in[1];
    float* out = (float*)d_out;
    dim3 grid(8, 32, 32);   // (j-tiles of 16 patches, i-tiles of 4 rows, batch)
    conv_mfma<<<grid, dim3(256, 1, 1), 0, stream>>>(x, w, out);
}

// Round 3
// 43.748 us; speedup vs baseline: 4.7057x; 1.8084x over previous
//
#include <hip/hip_runtime.h>

// out[b, i*4+p, j*4+q] = sum_k w[p*4+q][k] * patch(b,i,j)[k],  k = kh*16+kw
// MFMA 16x16x32 bf16, A = weights [16o x 32k], B = patches [32k x 16j] -> D[o][j].
// Block: 4 waves, wave = 1 patch-row, 4 j-tiles of 16 patches each.
// LDS strip: 40 rows x 520 cols bf16 (row padded to 576 els), XOR-swizzled 16B granules.

typedef __attribute__((ext_vector_type(8))) short short8;
typedef __attribute__((ext_vector_type(4))) float f32x4;

#define ROWS   40
#define ROWG   72          // 16B granules per LDS row (65 used + pad to mult of 8)
#define ROWE   (ROWG * 8)  // 576 bf16 elements per row
#define NG8    (ROWS * 65) // 2600 granules to stage

__device__ __forceinline__ unsigned short f2bf(float f) {
    unsigned int u = __builtin_bit_cast(unsigned int, f);
    u = (u + 0x7fffu + ((u >> 16) & 1u)) >> 16;   // RNE
    return (unsigned short)u;
}

__global__ __launch_bounds__(256, 3)
void conv_mfma2(const float* __restrict__ x,
                const float* __restrict__ w,
                float* __restrict__ out) {
    __shared__ unsigned short lds[ROWS * ROWE];   // 46080 B

    const int tid  = threadIdx.x;
    const int lane = tid & 63;
    const int wv   = tid >> 6;
    const int bx   = blockIdx.x;        // 0..63
    const int h    = bx & 1;            // column-strip half
    const int i0   = (bx >> 1) * 4;     // patch-row base
    const int b    = blockIdx.y;

    const float* xb = x + (size_t)b * (1024 * 1024);
    const int basecol = h * 504;        // strip h=1 starts at col 504 (patch 63)
    const int jb      = h * 63;         // first patch col of this strip

    // ---- weight fragment (A operand): lane holds w[o=lane&15][s*32+(lane>>4)*8+r]
    const int o = lane & 15;
    short8 wfrag[8];
    #pragma unroll
    for (int s = 0; s < 8; ++s) {
        const float* wp = w + o * 256 + s * 32 + (lane >> 4) * 8;
        float4 w0 = *(const float4*)wp;
        float4 w1 = *(const float4*)(wp + 4);
        short8 f;
        f[0] = (short)f2bf(w0.x); f[1] = (short)f2bf(w0.y);
        f[2] = (short)f2bf(w0.z); f[3] = (short)f2bf(w0.w);
        f[4] = (short)f2bf(w1.x); f[5] = (short)f2bf(w1.y);
        f[6] = (short)f2bf(w1.z); f[7] = (short)f2bf(w1.w);
        wfrag[s] = f;
    }

    // ---- stage x strip -> bf16 LDS, 16B granules, slot = c8 ^ (row&7) ----
    for (int it = 0; it < 11; ++it) {
        int g8 = tid + it * 256;
        if (g8 < NG8) {
            int row = g8 / 65;
            int c8  = g8 - row * 65;                 // 0..64
            int grow = i0 * 8 + row; if (grow > 1023) grow = 1023;
            const float* src = xb + grow * 1024 + basecol + c8 * 8;
            float4 v0 = *(const float4*)src;
            float4 v1 = *(const float4*)(src + 4);
            short8 hh;
            hh[0] = (short)f2bf(v0.x); hh[1] = (short)f2bf(v0.y);
            hh[2] = (short)f2bf(v0.z); hh[3] = (short)f2bf(v0.w);
            hh[4] = (short)f2bf(v1.x); hh[5] = (short)f2bf(v1.y);
            hh[6] = (short)f2bf(v1.z); hh[7] = (short)f2bf(v1.w);
            int slot = c8 ^ (row & 7);
            *(short8*)&lds[row * ROWE + slot * 8] = hh;
        }
    }
    __syncthreads();

    // ---- compute: wave wv -> patch row i0+wv; 4 j-tiles of 16 patches ----
    const int m  = lane & 15;           // patch col within tile
    const int kb = (lane >> 4) & 1;     // kw block (0/1)
    const int hi = lane >> 5;           // kh parity
    const int ip = i0 + wv;
    const int p  = lane >> 4;           // output sub-row 0..3

    #pragma unroll
    for (int jt = 0; jt < 4; ++jt) {
        const int gl = jt * 16 + m + kb;       // strip-local granule 0..64
        f32x4 acc = {0.f, 0.f, 0.f, 0.f};
        #pragma unroll
        for (int s = 0; s < 8; ++s) {
            int row  = wv * 8 + 2 * s + hi;
            int slot = gl ^ (row & 7);
            short8 a = *(const short8*)&lds[row * ROWE + slot * 8];
            acc = __builtin_amdgcn_mfma_f32_16x16x32_bf16(wfrag[s], a, acc, 0, 0, 0);
        }
        if (ip < 127) {
            const int jp = jb + jt * 16 + m;   // <= 126 by construction
            float* op = out + (size_t)b * (508 * 508) + (ip * 4 + p) * 508 + jp * 4;
            *(float4*)op = *(float4*)&acc;
        }
    }
}

extern "C" void kernel_launch(void* const* d_in, const int* in_sizes, int n_in,
                              void* d_out, int out_size, void* d_ws, size_t ws_size,
                              hipStream_t stream) {
    const float* x = (const float*)d_in[0];
    const float* w = (const float*)d_in[1];
    float* out = (float*)d_out;
    dim3 grid(64, 32);   // (i-tile x strip-half, batch)
    conv_mfma2<<<grid, dim3(256, 1, 1), 0, stream>>>(x, w, out);
}